// Round 1
// baseline (711.136 us; speedup 1.0000x reference)
//
#include <hip/hip_runtime.h>
#include <hip/hip_bf16.h>
#include <stdint.h>

#define AS1 __attribute__((address_space(1)))
#define AS3 __attribute__((address_space(3)))

typedef __bf16 bf16x8 __attribute__((ext_vector_type(8)));
typedef float floatx4 __attribute__((ext_vector_type(4)));

static constexpr int NTOK = 4096;   // B*T
static constexpr int H    = 1024;
static constexpr int DFF  = 4096;
static constexpr int E    = 8;
static constexpr int BM   = 128;
static constexpr int BN   = 128;
static constexpr int MAXROWS = 9216;          // 8192 pairs + 8*128 pad headroom

// ---- workspace layout (bytes) ----
static constexpr size_t OFF_WS    = 0;                       // 67,108,864  shuffled bf16 weights (w1 then w2)
static constexpr size_t OFF_XCS   = 67108864;                // 18,874,368  shuffled bf16 token rows
static constexpr size_t OFF_HS    = 85983232;                // 75,497,472  shuffled bf16 hidden
static constexpr size_t OFF_RTIDX = 161480704;               // 32 KB
static constexpr size_t OFF_RTW   = 161513472;               // 32 KB
static constexpr size_t OFF_PTOK  = 161546240;               // 36 KB
static constexpr size_t OFF_PW    = 161583104;               // 36 KB
static constexpr size_t OFF_CNT   = 161619968;               // 8+8+9 ints
static constexpr size_t WS_NEED   = 161620068;

__device__ __forceinline__ unsigned short f2bf(float f) {
    __bf16 b = (__bf16)f;
    return __builtin_bit_cast(unsigned short, b);
}

__device__ __forceinline__ void gload16(const void* g, void* l) {
    // dest = wave-uniform lds base; HW scatters lane i at base + i*16
    __builtin_amdgcn_global_load_lds((AS1 void*)g, (AS3 void*)l, 16, 0, 0);
}

// ---------------- router: fp32 logits, top-2, softmax ----------------
__global__ __launch_bounds__(256) void k_router(const float* __restrict__ x,
                                                const float* __restrict__ rw,
                                                int* __restrict__ rt_idx,
                                                float* __restrict__ rt_w,
                                                int* __restrict__ counts) {
    const int wv = threadIdx.x >> 6, ln = threadIdx.x & 63;
    const int t = blockIdx.x * 4 + wv;
    const float* xr = x + (size_t)t * H + ln * 4;
    float4 xv[4];
#pragma unroll
    for (int c = 0; c < 4; ++c) xv[c] = *(const float4*)(xr + c * 256);
    float lg[E];
#pragma unroll
    for (int e = 0; e < E; ++e) {
        const float* rr = rw + (size_t)e * H + ln * 4;
        float acc = 0.f;
#pragma unroll
        for (int c = 0; c < 4; ++c) {
            float4 rv = *(const float4*)(rr + c * 256);
            acc += xv[c].x * rv.x + xv[c].y * rv.y + xv[c].z * rv.z + xv[c].w * rv.w;
        }
#pragma unroll
        for (int s = 32; s > 0; s >>= 1) acc += __shfl_xor(acc, s, 64);
        lg[e] = acc;
    }
    if (ln == 0) {
        int i0 = 0; float v0 = lg[0];
#pragma unroll
        for (int e = 1; e < E; ++e) if (lg[e] > v0) { v0 = lg[e]; i0 = e; }
        int i1 = -1; float v1 = -INFINITY;
#pragma unroll
        for (int e = 0; e < E; ++e) if (e != i0 && lg[e] > v1) { v1 = lg[e]; i1 = e; }
        float e1 = expf(v1 - v0);
        float inv = 1.f / (1.f + e1);
        rt_idx[2 * t] = i0; rt_idx[2 * t + 1] = i1;
        rt_w[2 * t] = inv;  rt_w[2 * t + 1] = e1 * inv;
        atomicAdd(&counts[i0], 1);
        atomicAdd(&counts[i1], 1);
    }
}

// ---------------- padded prefix offsets ----------------
__global__ void k_offsets(const int* __restrict__ counts, int* __restrict__ offs) {
    if (threadIdx.x == 0) {
        int o = 0;
        for (int e = 0; e < E; ++e) { offs[e] = o; o += (counts[e] + BM - 1) & ~(BM - 1); }
        offs[E] = o;
    }
}

// ---------------- scatter pairs into expert segments ----------------
__global__ __launch_bounds__(256) void k_scatter(const int* __restrict__ rt_idx,
                                                 const float* __restrict__ rt_w,
                                                 const int* __restrict__ offs,
                                                 int* __restrict__ cursors,
                                                 int* __restrict__ pair_tok,
                                                 float* __restrict__ pair_w) {
    int t = blockIdx.x * 256 + threadIdx.x;
    if (t >= NTOK) return;
    for (int k = 0; k < 2; ++k) {
        int e = rt_idx[2 * t + k];
        int p = atomicAdd(&cursors[e], 1);
        int pos = offs[e] + p;
        pair_tok[pos] = t;
        pair_w[pos] = rt_w[2 * t + k];
    }
}

// ---------------- gather token rows -> bf16, octet-shuffled ----------------
// Xc_s[rb][kb][m][kq][j] = x[tok(pos)][kb*32+kq*8+j],  pos = rb*128+m ; pad rows = 0
__global__ __launch_bounds__(256) void k_gather(const float* __restrict__ x,
                                                const int* __restrict__ offs,
                                                const int* __restrict__ counts,
                                                const int* __restrict__ pair_tok,
                                                unsigned short* __restrict__ xcs) {
    int pos = blockIdx.x;
    if (pos >= offs[E]) return;
    int e = 0;
    while (e < E - 1 && pos >= offs[e + 1]) ++e;
    bool valid = (pos - offs[e]) < counts[e];
    int tok = valid ? pair_tok[pos] : 0;
    int k0 = threadIdx.x * 4;
    float4 xv = valid ? *(const float4*)(x + (size_t)tok * H + k0)
                      : make_float4(0.f, 0.f, 0.f, 0.f);
    ushort4 o;
    o.x = f2bf(xv.x); o.y = f2bf(xv.y); o.z = f2bf(xv.z); o.w = f2bf(xv.w);
    int rb = pos >> 7, m = pos & 127;
    size_t idx = (((size_t)(rb * 32 + (k0 >> 5)) * 128 + m) * 32) + (((k0 >> 3) & 3) << 3) + (k0 & 7);
    *(ushort4*)(xcs + idx) = o;
}

// ---------------- weight convert fp32 -> bf16, octet-shuffled ----------------
// Ws[e][kb][n][kq][j] = w[e][kb*32+kq*8+j][n]
template <int K, int N>
__global__ __launch_bounds__(256) void k_convert(const float* __restrict__ w,
                                                 unsigned short* __restrict__ ws) {
    constexpr int KB = K / 32, NB = N / 64;
    int bid = blockIdx.x;
    int nb = bid % NB, kb = (bid / NB) % KB, e = bid / (NB * KB);
    int kq = threadIdx.x & 3, nl = threadIdx.x >> 2;
    int n = nb * 64 + nl;
    const float* src = w + ((size_t)e * K + kb * 32 + kq * 8) * N + n;
    union { unsigned short us[8]; uint4 v; } u;
#pragma unroll
    for (int j = 0; j < 8; ++j) u.us[j] = f2bf(src[(size_t)j * N]);
    size_t oct = ((size_t)(e * KB + kb) * N + n) * 4 + kq;
    *(uint4*)(ws + oct * 8) = u.v;
}

// ---------------- MFMA GEMM, m97 structure ----------------
// A[m][k=quad*8+j] lane m=lane&15 ; B[k=quad*8+j][n=lane&15] ; D: col=lane&15, row=quad*4+r
template <int KTOT, int NTOT, bool IS_GEMM1>
__global__ __launch_bounds__(256) void k_gemm(const unsigned short* __restrict__ Asrc,
                                              const unsigned short* __restrict__ Bsrc,
                                              const int* __restrict__ counts,
                                              const int* __restrict__ offs,
                                              const float* __restrict__ bias,
                                              const int* __restrict__ pair_tok,
                                              const float* __restrict__ pair_w,
                                              unsigned short* __restrict__ Hs,
                                              float* __restrict__ out) {
    constexpr int KB = KTOT / 32;
    const int e = blockIdx.y >> 5, rt = blockIdx.y & 31;
    const int cnt = counts[e];
    if (rt * BM >= cnt) return;
    const int off = offs[e];
    const int rb = (off >> 7) + rt;
    const int n0 = blockIdx.x * BN;

    __shared__ unsigned short lds_a[BM * 32];
    __shared__ unsigned short lds_b[BN * 32];

    const int tid = threadIdx.x;
    const int wv = tid >> 6, ln = tid & 63;
    const int quad = ln >> 4, lr = ln & 15;
    const int wm = (wv & 1) * 64, wn = (wv >> 1) * 64;

    floatx4 acc[4][4];
#pragma unroll
    for (int i = 0; i < 4; ++i)
#pragma unroll
        for (int j = 0; j < 4; ++j) acc[i][j] = (floatx4){0.f, 0.f, 0.f, 0.f};

    const unsigned short* Atile = Asrc + (size_t)rb * KB * 4096;
    const unsigned short* Btile = Bsrc + ((size_t)e * KB * NTOT + n0) * 32;

    for (int kb = 0; kb < KB; ++kb) {
        __syncthreads();
        const unsigned short* a_src = Atile + (size_t)kb * 4096 + (wv * 2) * 512 + ln * 8;
        const unsigned short* b_src = Btile + (size_t)kb * NTOT * 32 + (wv * 2) * 512 + ln * 8;
#pragma unroll
        for (int c = 0; c < 2; ++c) {
            gload16(a_src + c * 512, &lds_a[(wv * 2 + c) * 512]);
            gload16(b_src + c * 512, &lds_b[(wv * 2 + c) * 512]);
        }
        __syncthreads();
        bf16x8 af[4], bg[4];
#pragma unroll
        for (int i = 0; i < 4; ++i) {
            af[i] = *(const bf16x8*)(lds_a + (wm + i * 16 + lr) * 32 + quad * 8);
            bg[i] = *(const bf16x8*)(lds_b + (wn + i * 16 + lr) * 32 + quad * 8);
        }
#pragma unroll
        for (int i = 0; i < 4; ++i)
#pragma unroll
            for (int j = 0; j < 4; ++j)
                acc[i][j] = __builtin_amdgcn_mfma_f32_16x16x32_bf16(af[i], bg[j], acc[i][j], 0, 0, 0);
    }

    if (IS_GEMM1) {
        float bj[4];
#pragma unroll
        for (int j = 0; j < 4; ++j) bj[j] = bias[(size_t)e * NTOT + n0 + wn + j * 16 + lr];
#pragma unroll
        for (int i = 0; i < 4; ++i) {
#pragma unroll
            for (int j = 0; j < 4; ++j) {
                const int f = n0 + wn + j * 16 + lr;
                const size_t fbase = (((size_t)rb * 128 + (f >> 5)) * 128) * 32 + (((f >> 3) & 3) << 3) + (f & 7);
#pragma unroll
                for (int r = 0; r < 4; ++r) {
                    const int m = wm + i * 16 + quad * 4 + r;
                    float v = acc[i][j][r] + bj[j];
                    float u = v + 0.044715f * v * v * v;
                    float tz = tanhf(0.79788456080286535588f * u);
                    float g = 0.5f * v * (1.f + tz);
                    Hs[fbase + (size_t)m * 32] = f2bf(g);
                }
            }
        }
    } else {
        float bj[4];
#pragma unroll
        for (int j = 0; j < 4; ++j) bj[j] = bias[(size_t)e * NTOT + n0 + wn + j * 16 + lr];
#pragma unroll
        for (int i = 0; i < 4; ++i) {
#pragma unroll
            for (int r = 0; r < 4; ++r) {
                const int m = wm + i * 16 + quad * 4 + r;
                const int lm = rt * BM + m;
                if (lm < cnt) {
                    const int pos = off + lm;
                    const int tok = pair_tok[pos];
                    const float wgt = pair_w[pos];
#pragma unroll
                    for (int j = 0; j < 4; ++j) {
                        const int n = n0 + wn + j * 16 + lr;
                        unsafeAtomicAdd(&out[(size_t)tok * H + n], wgt * (acc[i][j][r] + bj[j]));
                    }
                }
            }
        }
    }
}

extern "C" void kernel_launch(void* const* d_in, const int* in_sizes, int n_in,
                              void* d_out, int out_size, void* d_ws, size_t ws_size,
                              hipStream_t stream) {
    const float* x  = (const float*)d_in[0];
    const float* rw = (const float*)d_in[1];
    const float* w1 = (const float*)d_in[2];
    const float* b1 = (const float*)d_in[3];
    const float* w2 = (const float*)d_in[4];
    const float* b2 = (const float*)d_in[5];
    float* out = (float*)d_out;
    char* ws = (char*)d_ws;
    if (ws_size < WS_NEED) return;   // loud failure (out stays poisoned/zero)

    unsigned short* Ws   = (unsigned short*)(ws + OFF_WS);
    unsigned short* XcS  = (unsigned short*)(ws + OFF_XCS);
    unsigned short* Hs   = (unsigned short*)(ws + OFF_HS);
    int*   rt_idx   = (int*)(ws + OFF_RTIDX);
    float* rt_w     = (float*)(ws + OFF_RTW);
    int*   pair_tok = (int*)(ws + OFF_PTOK);
    float* pair_w   = (float*)(ws + OFF_PW);
    int*   cnt      = (int*)(ws + OFF_CNT);
    int*   cur      = cnt + 8;
    int*   offs     = cnt + 16;

    hipMemsetAsync(cnt, 0, 64, stream);                       // counts + cursors
    hipMemsetAsync(out, 0, (size_t)out_size * 4, stream);

    k_router<<<NTOK / 4, 256, 0, stream>>>(x, rw, rt_idx, rt_w, cnt);
    k_offsets<<<1, 64, 0, stream>>>(cnt, offs);
    k_scatter<<<NTOK / 256, 256, 0, stream>>>(rt_idx, rt_w, offs, cur, pair_tok, pair_w);
    k_gather<<<MAXROWS, 256, 0, stream>>>(x, offs, cnt, pair_tok, XcS);

    k_convert<H, DFF><<<8 * (H / 32) * (DFF / 64), 256, 0, stream>>>(w1, Ws);
    k_gemm<H, DFF, true><<<dim3(DFF / BN, 256), 256, 0, stream>>>(
        XcS, Ws, cnt, offs, b1, pair_tok, pair_w, Hs, out);

    k_convert<DFF, H><<<8 * (DFF / 32) * (H / 64), 256, 0, stream>>>(w2, Ws);
    k_gemm<DFF, H, false><<<dim3(H / BN, 256), 256, 0, stream>>>(
        Hs, Ws, cnt, offs, b2, pair_tok, pair_w, Hs, out);
}